// Round 4
// baseline (535.633 us; speedup 1.0000x reference)
//
#include <hip/hip_runtime.h>

// AdaMoeLayer: B=8,S=4096,D=512,E=8  -> T=32768 tokens
// out[t,f] = sum_e w[t,e] * ( x[t,:] @ W_exp[e] + b_exp[e] )[f]
// Round 4: 128x128 block tile (1.5x FLOP/staged-byte vs 128x64, half the
// barriers). Expert-outer: per expert tmp = bias-init MFMA accumulation,
// folded acc += w[t,e]*tmp in fp32. Both operands via global_load_lds w=16,
// XOR-swizzled LDS. Prep kernels merged into one launch.

#define T_TOKENS 32768
#define DDIM 512
#define KDIM 4096

typedef __attribute__((ext_vector_type(8))) short short8;
typedef __attribute__((ext_vector_type(4))) float floatx4;
typedef __bf16 bf16x2 __attribute__((ext_vector_type(2)));

__device__ __forceinline__ unsigned short f2bf(float f) {
    unsigned int u = __float_as_uint(f);
    u += 0x7FFFu + ((u >> 16) & 1u);   // RNE
    return (unsigned short)(u >> 16);
}

__device__ __forceinline__ unsigned int pk2(float a, float b) {
#if __has_builtin(__builtin_amdgcn_cvt_pk_bf16_f32)
    bf16x2 v = __builtin_amdgcn_cvt_pk_bf16_f32(a, b);
    return __builtin_bit_cast(unsigned int, v);
#else
    return (unsigned int)f2bf(a) | ((unsigned int)f2bf(b) << 16);
#endif
}

__device__ __forceinline__ void async_copy16(const void* g, void* l) {
    __builtin_amdgcn_global_load_lds(
        (const __attribute__((address_space(1))) void*)g,
        (__attribute__((address_space(3))) void*)l, 16, 0, 0);
}

// ---- Kernel 1 (merged prep): blocks [0,512): gating+x->bf16; [512,1024): Bt
__global__ __launch_bounds__(256) void prep_kernel(
    const float* __restrict__ x, const float* __restrict__ Wg,
    const float* __restrict__ bg, const float* __restrict__ Wt,
    const float* __restrict__ bt, const float* __restrict__ Wexp,
    float* __restrict__ wbuf, unsigned short* __restrict__ Xbf,
    unsigned short* __restrict__ Bt)
{
    __shared__ float smem[512 * 12];  // 24 KB; build_bt uses 64*65 of it
    const int tid = threadIdx.x;

    if (blockIdx.x < 512) {
        // ---------------- gating + conversion ----------------
        float* sW = smem;
        for (int i = tid; i < 512 * 9; i += 256) {
            int d = i / 9, e = i - d * 9;
            sW[d * 12 + e] = (e < 8) ? Wg[d * 8 + e] : Wt[d];
        }
        __syncthreads();

        const int t = blockIdx.x * 64 + (tid >> 2);
        const int q = tid & 3;
        float g[9];
#pragma unroll
        for (int e = 0; e < 9; ++e) g[e] = 0.f;

        const float4* xr = (const float4*)(x + (size_t)t * 512 + q * 128);
        for (int i = 0; i < 32; ++i) {
            float4 v = xr[i];
            float xv[4] = {v.x, v.y, v.z, v.w};
            const float* wp = &sW[(q * 128 + i * 4) * 12];
#pragma unroll
            for (int c = 0; c < 4; ++c) {
                const float* w = wp + c * 12;
#pragma unroll
                for (int e = 0; e < 9; ++e) g[e] = fmaf(xv[c], w[e], g[e]);
            }
        }
#pragma unroll
        for (int e = 0; e < 9; ++e) {
            g[e] += __shfl_xor(g[e], 1);
            g[e] += __shfl_xor(g[e], 2);
        }
        if (q == 0) {
#pragma unroll
            for (int e = 0; e < 8; ++e) g[e] += bg[e];
            g[8] += bt[0];
            float m = g[0];
#pragma unroll
            for (int e = 1; e < 8; ++e) m = fmaxf(m, g[e]);
            float s = 0.f;
            float p[8];
#pragma unroll
            for (int e = 0; e < 8; ++e) { p[e] = __expf(g[e] - m); s += p[e]; }
            const float inv = 1.f / s;
            const float thr = 0.25f / (1.f + __expf(-g[8]));
            float w8[8];
            float ws = 0.f;
#pragma unroll
            for (int e = 0; e < 8; ++e) {
                float a = p[e] * inv - thr;
                w8[e] = a > 0.f ? a : 0.f;
                ws += w8[e];
            }
            if (ws == 0.f) ws = 1.f;
            const float invw = 1.f / ws;
            float4 o0, o1;
            o0.x = w8[0] * invw; o0.y = w8[1] * invw;
            o0.z = w8[2] * invw; o0.w = w8[3] * invw;
            o1.x = w8[4] * invw; o1.y = w8[5] * invw;
            o1.z = w8[6] * invw; o1.w = w8[7] * invw;
            float4* op = (float4*)(wbuf + (size_t)t * 8);
            op[0] = o0;
            op[1] = o1;
        }

        // conversion: this block's 64 tokens (L2-hot from gating reads)
        const size_t base = (size_t)blockIdx.x * 64 * 512;
        const float4* xs = (const float4*)(x + base);
        uint2* xd = (uint2*)(Xbf + base);
#pragma unroll 4
        for (int it = 0; it < 32; ++it) {
            float4 v = xs[it * 256 + tid];
            uint2 pk;
            pk.x = pk2(v.x, v.y);
            pk.y = pk2(v.z, v.w);
            xd[it * 256 + tid] = pk;
        }
    } else {
        // ---------------- build Bt[512][4096] (transpose W_exp) ----------
        float (*tile)[65] = (float(*)[65])smem;
        const int lin = blockIdx.x - 512;
        const int k0 = (lin & 63) * 64;
        const int n0 = (lin >> 6) * 64;
        const int r = tid >> 4, cq = tid & 15;
#pragma unroll
        for (int p = 0; p < 4; ++p) {
            const int rr = p * 16 + r;
            const float4 v =
                *(const float4*)(Wexp + (size_t)(k0 + rr) * 512 + n0 + cq * 4);
            tile[rr][cq * 4 + 0] = v.x;
            tile[rr][cq * 4 + 1] = v.y;
            tile[rr][cq * 4 + 2] = v.z;
            tile[rr][cq * 4 + 3] = v.w;
        }
        __syncthreads();
        const int rn = tid >> 2;
        const int kq = tid & 3;
        alignas(16) unsigned short buf[16];
#pragma unroll
        for (int j = 0; j < 16; ++j) buf[j] = f2bf(tile[kq * 16 + j][rn]);
        unsigned short* dst = Bt + (size_t)(n0 + rn) * KDIM + k0 + kq * 16;
        *(uint4*)(dst) = *(const uint4*)(buf);
        *(uint4*)(dst + 8) = *(const uint4*)(buf + 8);
    }
}

// ------------- Kernel 2: main GEMM, 128x128 tile, expert-outer -------------
// LDS XOR-swizzle: (row,k) at row*64 + ((k/8 ^ (row&7))*8) + k%8 [shorts].
__global__ __launch_bounds__(256, 3) void moe_gemm(
    const unsigned short* __restrict__ Xbf, const float* __restrict__ wbuf,
    const float* __restrict__ bexp, const unsigned short* __restrict__ Bt,
    float* __restrict__ out)
{
    __shared__ alignas(16) unsigned short As[128 * 64];  // 16 KB
    __shared__ alignas(16) unsigned short Bs[128 * 64];  // 16 KB
    __shared__ float sWb[128 * 8];                       // 4 KB
    __shared__ float sBb[8 * 128];                       // 4 KB

    const int tid = threadIdx.x;
    const int wave = tid >> 6;
    const int lane = tid & 63;
    const int wm = wave >> 1;
    const int wn = wave & 1;
    const int lm = lane & 15;
    const int lq = lane >> 4;
    const int brow = lane >> 3;
    const int cg = (lane & 7) ^ brow;  // lane->global chunk permutation

    // XCD mapping: grid 1024, hw XCD = lin%8. n-tile = xcd&3 (Bt slice 1 MB
    // L2-resident), t-tiles split across xcd>>1 halves; Xbf (32 MB) sits in LLC.
    const int lin = blockIdx.x;
    const int g = lin & 7;
    const int j_ = lin >> 3;
    const int t0 = ((g >> 2) * 128 + j_) * 128;
    const int n0 = (g & 3) * 128;

    ((float4*)sWb)[tid] = ((const float4*)(wbuf + (size_t)t0 * 8))[tid];
    {   // bias slice: 8 experts x 128 cols
        const int e = tid >> 5, c4 = tid & 31;
        ((float4*)sBb)[tid] = *(const float4*)(bexp + (size_t)e * 512 + n0 + c4 * 4);
    }
    __syncthreads();

    floatx4 acc[4][4];
#pragma unroll
    for (int i = 0; i < 4; ++i)
#pragma unroll
        for (int j = 0; j < 4; ++j) acc[i][j] = (floatx4){0.f, 0.f, 0.f, 0.f};

    for (int e = 0; e < 8; ++e) {
        floatx4 tmp[4][4];
#pragma unroll
        for (int j = 0; j < 4; ++j) {
            const float bb = sBb[e * 128 + wn * 64 + j * 16 + lm];
#pragma unroll
            for (int i = 0; i < 4; ++i) tmp[i][j] = (floatx4){bb, bb, bb, bb};
        }

        for (int ks = 0; ks < 8; ++ks) {
            const int k0 = e * 512 + ks * 64;
            const int d0 = ks * 64 + cg * 8;

            // A staging: 4 DMA/wave (rows wave*32..wave*32+31)
#pragma unroll
            for (int i = 0; i < 4; ++i) {
                const int row = wave * 32 + i * 8 + brow;
                async_copy16(Xbf + (size_t)(t0 + row) * 512 + d0,
                             As + (wave * 32 + i * 8) * 64);
            }
            // B staging: 4 DMA/wave
#pragma unroll
            for (int i = 0; i < 4; ++i) {
                const int row = wave * 32 + i * 8 + brow;
                async_copy16(Bt + (size_t)(n0 + row) * KDIM + k0 + cg * 8,
                             Bs + (wave * 32 + i * 8) * 64);
            }
            __syncthreads();

#pragma unroll
            for (int kk = 0; kk < 2; ++kk) {
                const int ch = kk * 4 + lq;
                short8 a[4];
#pragma unroll
                for (int i = 0; i < 4; ++i) {
                    const int row = wm * 64 + i * 16 + lm;
                    a[i] = *(const short8*)(As + row * 64 + ((ch ^ (row & 7)) << 3));
                }
#pragma unroll
                for (int j = 0; j < 4; ++j) {
                    const int rowb = wn * 64 + j * 16 + lm;
                    const short8 b =
                        *(const short8*)(Bs + rowb * 64 + ((ch ^ (rowb & 7)) << 3));
#pragma unroll
                    for (int i = 0; i < 4; ++i)
                        tmp[i][j] = __builtin_amdgcn_mfma_f32_16x16x32_bf16(
                            a[i], b, tmp[i][j], 0, 0, 0);
                }
            }
            __syncthreads();
        }

        // fold: acc += w[t,e] * tmp  (fp32, per output row)
#pragma unroll
        for (int i = 0; i < 4; ++i)
#pragma unroll
            for (int r = 0; r < 4; ++r) {
                const float wv = sWb[(wm * 64 + i * 16 + lq * 4 + r) * 8 + e];
#pragma unroll
                for (int j = 0; j < 4; ++j)
                    acc[i][j][r] = fmaf(wv, tmp[i][j][r], acc[i][j][r]);
            }
    }

    // epilogue: C/D layout col=lane&15, row=(lane>>4)*4+reg
#pragma unroll
    for (int i = 0; i < 4; ++i)
#pragma unroll
        for (int r = 0; r < 4; ++r) {
            const size_t t = (size_t)t0 + wm * 64 + i * 16 + lq * 4 + r;
            float* op = out + t * 512 + n0 + wn * 64 + lm;
#pragma unroll
            for (int j = 0; j < 4; ++j) op[j * 16] = acc[i][j][r];
        }
}

extern "C" void kernel_launch(void* const* d_in, const int* in_sizes, int n_in,
                              void* d_out, int out_size, void* d_ws, size_t ws_size,
                              hipStream_t stream) {
    const float* x   = (const float*)d_in[0];
    const float* Wg  = (const float*)d_in[1];
    const float* bg  = (const float*)d_in[2];
    const float* Wt  = (const float*)d_in[3];
    const float* bt  = (const float*)d_in[4];
    const float* Wex = (const float*)d_in[5];
    const float* bex = (const float*)d_in[6];
    float* out = (float*)d_out;

    // ws: Xbf bf16 [32768][512] = 32 MB; Bt bf16 [512][4096] = 4 MB; wbuf 1 MB
    unsigned short* Xbf = (unsigned short*)d_ws;
    unsigned short* Bt  = (unsigned short*)((char*)d_ws + (size_t)T_TOKENS * DDIM * 2);
    float* wbuf = (float*)((char*)d_ws + (size_t)T_TOKENS * DDIM * 2
                                       + (size_t)DDIM * KDIM * 2);

    prep_kernel<<<1024, 256, 0, stream>>>(x, Wg, bg, Wt, bt, Wex, wbuf, Xbf, Bt);
    moe_gemm<<<1024, 256, 0, stream>>>(Xbf, wbuf, bex, Bt, out);
}

// Round 5
// 424.127 us; speedup vs baseline: 1.2629x; 1.2629x over previous
//
#include <hip/hip_runtime.h>

// AdaMoeLayer: B=8,S=4096,D=512,E=8  -> T=32768 tokens
// out[t,f] = sum_e w[t,e] * ( x[t,:] @ W_exp[e] + b_exp[e] )[f]
// Round 5: R3 GEMM structure (128x64 tile, expert-outer fold, DMA staging,
// proven 256us) + gate-sparsity: tokens counting-sorted by 8-bit selection
// mask so tiles are mask-homogeneous; experts absent from a tile's OR-mask
// are skipped (exact: their w==0 rows contribute 0). ~3-4/8 experts/tile.

#define T_TOKENS 32768
#define DDIM 512
#define KDIM 4096

typedef __attribute__((ext_vector_type(8))) short short8;
typedef __attribute__((ext_vector_type(4))) float floatx4;
typedef __bf16 bf16x2 __attribute__((ext_vector_type(2)));

__device__ __forceinline__ unsigned short f2bf(float f) {
    unsigned int u = __float_as_uint(f);
    u += 0x7FFFu + ((u >> 16) & 1u);   // RNE
    return (unsigned short)(u >> 16);
}

__device__ __forceinline__ unsigned int pk2(float a, float b) {
#if __has_builtin(__builtin_amdgcn_cvt_pk_bf16_f32)
    bf16x2 v = __builtin_amdgcn_cvt_pk_bf16_f32(a, b);
    return __builtin_bit_cast(unsigned int, v);
#else
    return (unsigned int)f2bf(a) | ((unsigned int)f2bf(b) << 16);
#endif
}

__device__ __forceinline__ void async_copy16(const void* g, void* l) {
    __builtin_amdgcn_global_load_lds(
        (const __attribute__((address_space(1))) void*)g,
        (__attribute__((address_space(3))) void*)l, 16, 0, 0);
}

// ---- Kernel 1 (merged prep): blocks [0,512): gating+mask+x->bf16;
// ----                         blocks [512,1024): Bt transpose
__global__ __launch_bounds__(256) void prep_kernel(
    const float* __restrict__ x, const float* __restrict__ Wg,
    const float* __restrict__ bg, const float* __restrict__ Wt,
    const float* __restrict__ bt, const float* __restrict__ Wexp,
    float* __restrict__ wbuf, unsigned short* __restrict__ Xbf,
    unsigned short* __restrict__ Bt, int* __restrict__ maskb)
{
    __shared__ float smem[512 * 12];  // 24 KB; Bt path uses 64*65 of it
    const int tid = threadIdx.x;

    if (blockIdx.x < 512) {
        float* sW = smem;
        for (int i = tid; i < 512 * 9; i += 256) {
            int d = i / 9, e = i - d * 9;
            sW[d * 12 + e] = (e < 8) ? Wg[d * 8 + e] : Wt[d];
        }
        __syncthreads();

        const int t = blockIdx.x * 64 + (tid >> 2);
        const int q = tid & 3;
        float g[9];
#pragma unroll
        for (int e = 0; e < 9; ++e) g[e] = 0.f;

        const float4* xr = (const float4*)(x + (size_t)t * 512 + q * 128);
        for (int i = 0; i < 32; ++i) {
            float4 v = xr[i];
            float xv[4] = {v.x, v.y, v.z, v.w};
            const float* wp = &sW[(q * 128 + i * 4) * 12];
#pragma unroll
            for (int c = 0; c < 4; ++c) {
                const float* w = wp + c * 12;
#pragma unroll
                for (int e = 0; e < 9; ++e) g[e] = fmaf(xv[c], w[e], g[e]);
            }
        }
#pragma unroll
        for (int e = 0; e < 9; ++e) {
            g[e] += __shfl_xor(g[e], 1);
            g[e] += __shfl_xor(g[e], 2);
        }
        if (q == 0) {
#pragma unroll
            for (int e = 0; e < 8; ++e) g[e] += bg[e];
            g[8] += bt[0];
            float m = g[0];
#pragma unroll
            for (int e = 1; e < 8; ++e) m = fmaxf(m, g[e]);
            float s = 0.f;
            float p[8];
#pragma unroll
            for (int e = 0; e < 8; ++e) { p[e] = __expf(g[e] - m); s += p[e]; }
            const float inv = 1.f / s;
            const float thr = 0.25f / (1.f + __expf(-g[8]));
            float w8[8];
            float ws = 0.f;
            int msk = 0;
#pragma unroll
            for (int e = 0; e < 8; ++e) {
                float a = p[e] * inv - thr;
                w8[e] = a > 0.f ? a : 0.f;
                if (w8[e] > 0.f) msk |= (1 << e);
                ws += w8[e];
            }
            if (ws == 0.f) ws = 1.f;
            const float invw = 1.f / ws;
            float4 o0, o1;
            o0.x = w8[0] * invw; o0.y = w8[1] * invw;
            o0.z = w8[2] * invw; o0.w = w8[3] * invw;
            o1.x = w8[4] * invw; o1.y = w8[5] * invw;
            o1.z = w8[6] * invw; o1.w = w8[7] * invw;
            float4* op = (float4*)(wbuf + (size_t)t * 8);
            op[0] = o0;
            op[1] = o1;
            maskb[t] = msk;
        }

        const size_t base = (size_t)blockIdx.x * 64 * 512;
        const float4* xs = (const float4*)(x + base);
        uint2* xd = (uint2*)(Xbf + base);
#pragma unroll 4
        for (int it = 0; it < 32; ++it) {
            float4 v = xs[it * 256 + tid];
            uint2 pk;
            pk.x = pk2(v.x, v.y);
            pk.y = pk2(v.z, v.w);
            xd[it * 256 + tid] = pk;
        }
    } else {
        float (*tile)[65] = (float(*)[65])smem;
        const int lin = blockIdx.x - 512;
        const int k0 = (lin & 63) * 64;
        const int n0 = (lin >> 6) * 64;
        const int r = tid >> 4, cq = tid & 15;
#pragma unroll
        for (int p = 0; p < 4; ++p) {
            const int rr = p * 16 + r;
            const float4 v =
                *(const float4*)(Wexp + (size_t)(k0 + rr) * 512 + n0 + cq * 4);
            tile[rr][cq * 4 + 0] = v.x;
            tile[rr][cq * 4 + 1] = v.y;
            tile[rr][cq * 4 + 2] = v.z;
            tile[rr][cq * 4 + 3] = v.w;
        }
        __syncthreads();
        const int rn = tid >> 2;
        const int kq = tid & 3;
        alignas(16) unsigned short buf[16];
#pragma unroll
        for (int j = 0; j < 16; ++j) buf[j] = f2bf(tile[kq * 16 + j][rn]);
        unsigned short* dst = Bt + (size_t)(n0 + rn) * KDIM + k0 + kq * 16;
        *(uint4*)(dst) = *(const uint4*)(buf);
        *(uint4*)(dst + 8) = *(const uint4*)(buf + 8);
    }
}

// ---- Kernel 2: histogram of 256 masks + exclusive scan -> cursor ----
__global__ __launch_bounds__(256) void scan_kernel(
    const int* __restrict__ maskb, int* __restrict__ cursor)
{
    __shared__ int cnt[256];
    __shared__ int sa[256], sb[256];
    const int tid = threadIdx.x;
    cnt[tid] = 0;
    __syncthreads();
    for (int i = tid; i < T_TOKENS; i += 256)
        atomicAdd(&cnt[maskb[i]], 1);
    __syncthreads();
    sa[tid] = cnt[tid];
    __syncthreads();
    int* src = sa;
    int* dst = sb;
    for (int off = 1; off < 256; off <<= 1) {
        int v = src[tid];
        if (tid >= off) v += src[tid - off];
        dst[tid] = v;
        __syncthreads();
        int* tswap = src; src = dst; dst = tswap;
    }
    cursor[tid] = src[tid] - cnt[tid];  // exclusive
}

// ---- Kernel 3: scatter tokens into mask-sorted order ----
__global__ __launch_bounds__(256) void scatter_kernel(
    const int* __restrict__ maskb, int* __restrict__ cursor,
    int* __restrict__ perm)
{
    const int t = blockIdx.x * 256 + threadIdx.x;
    const int m = maskb[t];
    const int pos = atomicAdd(&cursor[m], 1);
    perm[pos] = t;
}

// ---- Kernel 4: main GEMM (R3 config) + gather rows + expert skip ----
// LDS XOR-swizzle: (row,k) at row*64 + ((k/8 ^ (row&7))*8) + k%8 [shorts].
__global__ __launch_bounds__(256, 4) void moe_gemm(
    const unsigned short* __restrict__ Xbf, const float* __restrict__ wbuf,
    const float* __restrict__ bexp, const unsigned short* __restrict__ Bt,
    const int* __restrict__ perm, const int* __restrict__ maskb,
    float* __restrict__ out)
{
    __shared__ alignas(16) unsigned short As[128 * 64];  // 16 KB
    __shared__ alignas(16) unsigned short Bs[64 * 64];   // 8 KB
    __shared__ float sWb[128 * 8];                       // 4 KB
    __shared__ float sBb[8 * 64];                        // 2 KB
    __shared__ int sRow[128];
    __shared__ unsigned tmask;

    const int tid = threadIdx.x;
    const int wave = tid >> 6;
    const int lane = tid & 63;
    const int wm = wave >> 1;
    const int wn = wave & 1;
    const int lm = lane & 15;
    const int lq = lane >> 4;
    const int brow = lane >> 3;
    const int cg = (lane & 7) ^ brow;  // lane->global chunk permutation

    // R3 XCD mapping: grid 2048; XCD g = lin%8 owns t-tiles g*32..g*32+31;
    // a t-tile's 8 n-blocks are consecutive lin (co-resident, share L2).
    const int lin = blockIdx.x;
    const int g = lin & 7;
    const int j_ = lin >> 3;
    const int t0 = (g * 32 + (j_ >> 3)) * 128;  // offset in PERMUTED space
    const int n0 = (j_ & 7) * 64;

    if (tid == 0) tmask = 0u;
    __syncthreads();
    if (tid < 128) {
        const int r = perm[t0 + tid];
        sRow[tid] = r;
        atomicOr(&tmask, (unsigned)maskb[r]);
    }
    __syncthreads();
    {   // gather gate weights
        const int i = tid >> 1, h = tid & 1;
        ((float4*)(sWb + i * 8))[h] =
            ((const float4*)(wbuf + (size_t)sRow[i] * 8))[h];
    }
    if (tid < 128) {  // bias slice: 8 experts x 64 cols
        const int e = tid >> 4, c4 = tid & 15;
        ((float4*)sBb)[tid] = *(const float4*)(bexp + (size_t)e * 512 + n0 + c4 * 4);
    }
    __syncthreads();
    const unsigned tileMask = tmask;

    // per-thread gathered A base pointers (rows fixed across the k-loop)
    const unsigned short* aPtr[4];
#pragma unroll
    for (int i = 0; i < 4; ++i)
        aPtr[i] = Xbf + (size_t)sRow[wave * 32 + i * 8 + brow] * 512 + cg * 8;

    floatx4 acc[4][2];
#pragma unroll
    for (int i = 0; i < 4; ++i) {
        acc[i][0] = (floatx4){0.f, 0.f, 0.f, 0.f};
        acc[i][1] = (floatx4){0.f, 0.f, 0.f, 0.f};
    }

    for (int e = 0; e < 8; ++e) {
        if (!((tileMask >> e) & 1u)) continue;  // exact: all w[:,e]==0 in tile

        const float bb0 = sBb[e * 64 + wn * 32 + lm];
        const float bb1 = sBb[e * 64 + wn * 32 + 16 + lm];
        floatx4 tmp[4][2];
#pragma unroll
        for (int i = 0; i < 4; ++i) {
            tmp[i][0] = (floatx4){bb0, bb0, bb0, bb0};
            tmp[i][1] = (floatx4){bb1, bb1, bb1, bb1};
        }

        for (int ks = 0; ks < 8; ++ks) {
            const int k0 = e * 512 + ks * 64;

            // A staging: 4 DMA/wave, gathered rows
#pragma unroll
            for (int i = 0; i < 4; ++i)
                async_copy16(aPtr[i] + ks * 64, As + (wave * 32 + i * 8) * 64);
            // B staging: 2 DMA/wave
#pragma unroll
            for (int i = 0; i < 2; ++i) {
                const int row = wave * 16 + i * 8 + brow;
                async_copy16(Bt + (size_t)(n0 + row) * KDIM + k0 + cg * 8,
                             Bs + (wave * 16 + i * 8) * 64);
            }
            __syncthreads();

#pragma unroll
            for (int kk = 0; kk < 2; ++kk) {
                const int ch = kk * 4 + lq;
                short8 a[4], b[2];
#pragma unroll
                for (int i = 0; i < 4; ++i) {
                    const int row = wm * 64 + i * 16 + lm;
                    a[i] = *(const short8*)(As + row * 64 + ((ch ^ (row & 7)) << 3));
                }
#pragma unroll
                for (int j = 0; j < 2; ++j) {
                    const int row = wn * 32 + j * 16 + lm;
                    b[j] = *(const short8*)(Bs + row * 64 + ((ch ^ (row & 7)) << 3));
                }
#pragma unroll
                for (int i = 0; i < 4; ++i)
#pragma unroll
                    for (int j = 0; j < 2; ++j)
                        tmp[i][j] = __builtin_amdgcn_mfma_f32_16x16x32_bf16(
                            a[i], b[j], tmp[i][j], 0, 0, 0);
            }
            __syncthreads();
        }

        // fold: acc += w[t,e] * tmp (w==0 rows add exactly 0)
#pragma unroll
        for (int i = 0; i < 4; ++i)
#pragma unroll
            for (int r = 0; r < 4; ++r) {
                const float wv = sWb[(wm * 64 + i * 16 + lq * 4 + r) * 8 + e];
                acc[i][0][r] = fmaf(wv, tmp[i][0][r], acc[i][0][r]);
                acc[i][1][r] = fmaf(wv, tmp[i][1][r], acc[i][1][r]);
            }
    }

    // epilogue: scatter rows; C/D layout col=lane&15, row=(lane>>4)*4+reg
#pragma unroll
    for (int i = 0; i < 4; ++i)
#pragma unroll
        for (int r = 0; r < 4; ++r) {
            const size_t t = (size_t)sRow[wm * 64 + i * 16 + lq * 4 + r];
            float* op = out + t * 512 + n0 + wn * 32 + lm;
            op[0] = acc[i][0][r];
            op[16] = acc[i][1][r];
        }
}

extern "C" void kernel_launch(void* const* d_in, const int* in_sizes, int n_in,
                              void* d_out, int out_size, void* d_ws, size_t ws_size,
                              hipStream_t stream) {
    const float* x   = (const float*)d_in[0];
    const float* Wg  = (const float*)d_in[1];
    const float* bg  = (const float*)d_in[2];
    const float* Wt  = (const float*)d_in[3];
    const float* bt  = (const float*)d_in[4];
    const float* Wex = (const float*)d_in[5];
    const float* bex = (const float*)d_in[6];
    float* out = (float*)d_out;

    // ws: Xbf 32MB | Bt 4MB | wbuf 1MB | maskb 128KB | perm 128KB | cursor 1KB
    char* p = (char*)d_ws;
    unsigned short* Xbf = (unsigned short*)p;            p += (size_t)T_TOKENS * DDIM * 2;
    unsigned short* Bt  = (unsigned short*)p;            p += (size_t)DDIM * KDIM * 2;
    float* wbuf = (float*)p;                             p += (size_t)T_TOKENS * 8 * 4;
    int* maskb = (int*)p;                                p += (size_t)T_TOKENS * 4;
    int* perm  = (int*)p;                                p += (size_t)T_TOKENS * 4;
    int* cursor = (int*)p;

    prep_kernel<<<1024, 256, 0, stream>>>(x, Wg, bg, Wt, bt, Wex, wbuf, Xbf, Bt, maskb);
    scan_kernel<<<1, 256, 0, stream>>>(maskb, cursor);
    scatter_kernel<<<T_TOKENS / 256, 256, 0, stream>>>(maskb, cursor, perm);
    moe_gemm<<<2048, 256, 0, stream>>>(Xbf, wbuf, bex, Bt, perm, maskb, out);
}